// Round 16
// baseline (64.656 us; speedup 1.0000x reference)
//
#include <hip/hip_runtime.h>

// Problem constants
#define B_     64
#define L_     1024
#define D_     1280   // 320 float4
#define H1_    640
#define H2_    320
#define NSPLIT 16     // per-batch even-split stripes
#define KS_    16     // k-splits for mlp1
#define KC_    80     // 1280/16
#define NJT_   10     // W1 j-tiles of 64
#define NJT2_  5      // W2 j-tiles of 64

// ---------------- Kernel 1: per-batch even-split stripe partial sums ----------------
// BYTE-IDENTICAL to R15 (probe-verified at HBM ceiling).
__global__ void pool_partial(const float* __restrict__ rep, const int* __restrict__ blen,
                             float* __restrict__ part) {
    const int s   = blockIdx.x;     // stripe
    const int b   = blockIdx.y;     // batch
    const int tid = threadIdx.x;    // 0..319 (float4 lane)
    const int n   = blen[b] - 2;    // valid rows (>=1)

    const int l0 = 1 + (s * n) / NSPLIT;
    const int l1 = 1 + ((s + 1) * n) / NSPLIT;

    float4 acc = make_float4(0.f, 0.f, 0.f, 0.f);
    const float4* base = (const float4*)rep + (size_t)b * L_ * (D_ / 4) + tid;
    #pragma unroll 8
    for (int l = l0; l < l1; ++l) {
        float4 v = base[(size_t)l * (D_ / 4)];
        acc.x += v.x; acc.y += v.y; acc.z += v.z; acc.w += v.w;
    }
    ((float4*)part)[((size_t)b * NSPLIT + s) * (D_ / 4) + tid] = acc;
}

// ---------------- Kernel 2: stripe reduce -> pooled (R15, byte-identical) ------------
__global__ void pool_reduce(const float* __restrict__ part, const int* __restrict__ blen,
                            float* __restrict__ pooled) {
    const int qt  = blockIdx.x;     // col quarter-tile 0..4
    const int b   = blockIdx.y;     // batch
    const int tid = threadIdx.x;    // 0..63
    const int col = qt * 64 + tid;  // float4 column 0..319

    int n = blen[b] - 2; if (n < 1) n = 1;
    const float inv = 1.0f / (float)n;
    const float4* p = (const float4*)part + (size_t)b * NSPLIT * (D_ / 4) + col;
    float4 a = make_float4(0.f, 0.f, 0.f, 0.f);
    #pragma unroll
    for (int s = 0; s < NSPLIT; ++s) {
        float4 v = p[(size_t)s * (D_ / 4)];
        a.x += v.x; a.y += v.y; a.z += v.z; a.w += v.w;
    }
    ((float4*)pooled)[(size_t)b * (D_ / 4) + col] =
        make_float4(a.x * inv, a.y * inv, a.z * inv, a.w * inv);
}

// ---------------- Kernel 3: mlp1 partials (R15, byte-identical) ----------------
__global__ void mlp1_partial(const float* __restrict__ pooled, const float* __restrict__ W1,
                             float* __restrict__ hpart) {
    const int jt  = blockIdx.x;     // 0..9
    const int ks  = blockIdx.y;     // 0..15
    const int tid = threadIdx.x;    // 0..511
    const int jl  = tid & 63;
    const int b0  = (tid >> 6) * 8;
    const int k0  = ks * KC_;
    const int j0  = jt * 64;

    __shared__ float pl[B_][KC_];   // pooled k-slice (20 KB)
    for (int e = tid; e < B_ * (KC_ / 4); e += 512) {
        const int b   = e / (KC_ / 4);
        const int kk4 = e % (KC_ / 4);
        float4 v = ((const float4*)pooled)[(size_t)b * (D_ / 4) + (k0 / 4) + kk4];
        *(float4*)&pl[b][kk4 * 4] = v;
    }
    __syncthreads();

    float acc[8];
    #pragma unroll
    for (int r = 0; r < 8; ++r) acc[r] = 0.f;

    const float* w1p = W1 + (size_t)k0 * H1_ + j0 + jl;
    for (int kk = 0; kk < KC_; kk += 4) {
        const float w0 = w1p[(size_t)(kk + 0) * H1_];
        const float w1 = w1p[(size_t)(kk + 1) * H1_];
        const float w2 = w1p[(size_t)(kk + 2) * H1_];
        const float w3 = w1p[(size_t)(kk + 3) * H1_];
        #pragma unroll
        for (int r = 0; r < 8; ++r) {
            float4 pv = *(const float4*)&pl[b0 + r][kk];
            acc[r] = fmaf(pv.x, w0, acc[r]);
            acc[r] = fmaf(pv.y, w1, acc[r]);
            acc[r] = fmaf(pv.z, w2, acc[r]);
            acc[r] = fmaf(pv.w, w3, acc[r]);
        }
    }
    #pragma unroll
    for (int r = 0; r < 8; ++r)
        hpart[((size_t)(b0 + r) * KS_ + ks) * H1_ + j0 + jl] = acc[r];
}

// ---------------- Kernel 4: h-reduce + W2 j-slice -> emb (R15, byte-identical) -------
__global__ void mlp2(const float* __restrict__ hpart, const float* __restrict__ b1,
                     const float* __restrict__ W2, const float* __restrict__ b2,
                     float* __restrict__ out) {
    const int jt  = blockIdx.x;     // 0..4
    const int b   = blockIdx.y;     // 0..63
    const int tid = threadIdx.x;    // 0..511
    const int jl  = tid & 63;
    const int kq  = tid >> 6;       // 0..7
    const int j   = jt * 64 + jl;

    __shared__ float hrow[H1_];     // 2.56 KB
    __shared__ float pt[8][64];     // 2 KB

    const float* hb = hpart + (size_t)b * KS_ * H1_;
    for (int jj = tid; jj < H1_; jj += 512) {
        float s = b1[jj];
        #pragma unroll
        for (int ks = 0; ks < KS_; ++ks)
            s += hb[(size_t)ks * H1_ + jj];
        hrow[jj] = fmaxf(s, 0.f);
    }
    __syncthreads();

    float a0 = 0.f, a1 = 0.f, a2 = 0.f, a3 = 0.f;
    const int kbeg = kq * (H1_ / 8);
    const float* w = W2 + (size_t)kbeg * H2_ + j;
    #pragma unroll 5
    for (int k = 0; k < H1_ / 8; k += 4) {
        const float4 hv = *(const float4*)&hrow[kbeg + k];   // wave-uniform broadcast
        a0 = fmaf(hv.x, w[(size_t)(k + 0) * H2_], a0);
        a1 = fmaf(hv.y, w[(size_t)(k + 1) * H2_], a1);
        a2 = fmaf(hv.z, w[(size_t)(k + 2) * H2_], a2);
        a3 = fmaf(hv.w, w[(size_t)(k + 3) * H2_], a3);
    }
    pt[kq][jl] = (a0 + a1) + (a2 + a3);
    __syncthreads();

    if (tid < 64) {
        float e = b2[j];
        #pragma unroll
        for (int q = 0; q < 8; ++q) e += pt[q][jl];
        out[128 + (size_t)b * H2_ + j] = fmaxf(e, 0.f);
    }
}

// ---------------- Kernel 5: y = emb @ W3 + b3 (R15, byte-identical) ----------------
__global__ void mlp3(const float* __restrict__ out_emb, const float* __restrict__ W3,
                     const float* __restrict__ b3, float* __restrict__ out) {
    const int b    = blockIdx.x;
    const int lane = threadIdx.x;   // 0..63
    float s0 = 0.f, s1 = 0.f;
    #pragma unroll
    for (int i = 0; i < H2_ / 64; ++i) {
        const int jj = lane + i * 64;
        const float e = out_emb[128 + (size_t)b * H2_ + jj];
        s0 = fmaf(e, W3[(size_t)jj * 2 + 0], s0);
        s1 = fmaf(e, W3[(size_t)jj * 2 + 1], s1);
    }
    #pragma unroll
    for (int off = 32; off >= 1; off >>= 1) {
        s0 += __shfl_xor(s0, off, 64);
        s1 += __shfl_xor(s1, off, 64);
    }
    if (lane == 0) {
        out[(size_t)b * 2 + 0] = s0 + b3[0];
        out[(size_t)b * 2 + 1] = s1 + b3[1];
    }
}

extern "C" void kernel_launch(void* const* d_in, const int* in_sizes, int n_in,
                              void* d_out, int out_size, void* d_ws, size_t ws_size,
                              hipStream_t stream) {
    const float* rep  = (const float*)d_in[0];
    const int*   blen = (const int*)  d_in[1];
    const float* W1   = (const float*)d_in[2];
    const float* b1   = (const float*)d_in[3];
    const float* W2   = (const float*)d_in[4];
    const float* b2   = (const float*)d_in[5];
    const float* W3   = (const float*)d_in[6];
    const float* b3   = (const float*)d_in[7];
    float* out = (float*)d_out;

    float* ws     = (float*)d_ws;
    float* part   = ws;
    float* pooled = part + (size_t)B_ * NSPLIT * D_;
    float* hpart  = pooled + (size_t)B_ * D_;

    // TIMING PROBE: all four tail kernels launched twice (each is a pure
    // function of its inputs -> identical rewrite, deterministic output).
    // dur_us(R16) - dur_us(R15) == sum of the four tail kernels' warm durations.
    pool_partial<<<dim3(NSPLIT, B_), 320, 0, stream>>>(rep, blen, part);
    pool_reduce <<<dim3(5, B_), 64, 0, stream>>>(part, blen, pooled);
    pool_reduce <<<dim3(5, B_), 64, 0, stream>>>(part, blen, pooled);
    mlp1_partial<<<dim3(NJT_, KS_), 512, 0, stream>>>(pooled, W1, hpart);
    mlp1_partial<<<dim3(NJT_, KS_), 512, 0, stream>>>(pooled, W1, hpart);
    mlp2        <<<dim3(NJT2_, B_), 512, 0, stream>>>(hpart, b1, W2, b2, out);
    mlp2        <<<dim3(NJT2_, B_), 512, 0, stream>>>(hpart, b1, W2, b2, out);
    mlp3        <<<B_, 64, 0, stream>>>(out, W3, b3, out);
    mlp3        <<<B_, 64, 0, stream>>>(out, W3, b3, out);
}

// Round 17
// 49.037 us; speedup vs baseline: 1.3185x; 1.3185x over previous
//
#include <hip/hip_runtime.h>

// Problem constants
#define B_     64
#define L_     1024
#define D_     1280   // 320 float4
#define H1_    640
#define H2_    320
#define NSPLIT 16     // per-batch even-split stripes
#define KS_    16     // k-splits for mlp1
#define KC_    80     // 1280/16
#define NJT_   20     // W1 j-tiles of 32 (320 blocks -> all 256 CUs)
#define NJT2_  5      // W2 j-tiles of 64

// ---------------- Kernel 1: per-batch even-split stripe partial sums ----------------
// BYTE-IDENTICAL to R15 (probe-verified at HBM ceiling, 25.5us).
__global__ void pool_partial(const float* __restrict__ rep, const int* __restrict__ blen,
                             float* __restrict__ part) {
    const int s   = blockIdx.x;     // stripe
    const int b   = blockIdx.y;     // batch
    const int tid = threadIdx.x;    // 0..319 (float4 lane)
    const int n   = blen[b] - 2;    // valid rows (>=1)

    const int l0 = 1 + (s * n) / NSPLIT;
    const int l1 = 1 + ((s + 1) * n) / NSPLIT;

    float4 acc = make_float4(0.f, 0.f, 0.f, 0.f);
    const float4* base = (const float4*)rep + (size_t)b * L_ * (D_ / 4) + tid;
    #pragma unroll 8
    for (int l = l0; l < l1; ++l) {
        float4 v = base[(size_t)l * (D_ / 4)];
        acc.x += v.x; acc.y += v.y; acc.z += v.z; acc.w += v.w;
    }
    ((float4*)part)[((size_t)b * NSPLIT + s) * (D_ / 4) + tid] = acc;
}

// ---------------- Kernel 2: stripe reduce -> pooled (widened: 4 waves/block) --------
// grid (5, B_) = 320 blocks x 256 thr. Thread (sg=tid>>6, c=tid&63) sums 4
// stripes; LDS combine. 4 waves hide the dependent-load chain (was 1 wave).
__global__ void pool_reduce(const float* __restrict__ part, const int* __restrict__ blen,
                            float* __restrict__ pooled) {
    const int qt  = blockIdx.x;     // col quarter-tile 0..4
    const int b   = blockIdx.y;     // batch
    const int tid = threadIdx.x;    // 0..255
    const int c   = tid & 63;
    const int sg  = tid >> 6;       // stripe group 0..3
    const int col = qt * 64 + c;    // float4 column 0..319

    __shared__ float4 tmp[4][64];

    const float4* p = (const float4*)part + ((size_t)b * NSPLIT + sg * 4) * (D_ / 4) + col;
    float4 a = make_float4(0.f, 0.f, 0.f, 0.f);
    #pragma unroll
    for (int s = 0; s < 4; ++s) {
        float4 v = p[(size_t)s * (D_ / 4)];
        a.x += v.x; a.y += v.y; a.z += v.z; a.w += v.w;
    }
    tmp[sg][c] = a;
    __syncthreads();

    if (tid < 64) {
        int n = blen[b] - 2; if (n < 1) n = 1;
        const float inv = 1.0f / (float)n;
        float4 t0 = tmp[0][c], t1 = tmp[1][c], t2 = tmp[2][c], t3 = tmp[3][c];
        float4 r = make_float4((t0.x + t1.x) + (t2.x + t3.x),
                               (t0.y + t1.y) + (t2.y + t3.y),
                               (t0.z + t1.z) + (t2.z + t3.z),
                               (t0.w + t1.w) + (t2.w + t3.w));
        ((float4*)pooled)[(size_t)b * (D_ / 4) + col] =
            make_float4(r.x * inv, r.y * inv, r.z * inv, r.w * inv);
    }
}

// ---------------- Kernel 3: mlp1 partials, widened to 320 blocks ----------------
// grid (NJT_=20, KS_=16) = 320 blocks x 256 thr — all 256 CUs (was 160).
// Thread owns 8 batches x 1 col (jl = tid&31, j-tile of 32). W1 read ONCE
// grid-wide; 128B-coalesced per half-wave, L1/L2 broadcast across b-groups.
__global__ void mlp1_partial(const float* __restrict__ pooled, const float* __restrict__ W1,
                             float* __restrict__ hpart) {
    const int jt  = blockIdx.x;     // 0..19
    const int ks  = blockIdx.y;     // 0..15
    const int tid = threadIdx.x;    // 0..255
    const int jl  = tid & 31;
    const int b0  = (tid >> 5) * 8; // 8 batch-groups of 8
    const int k0  = ks * KC_;
    const int j0  = jt * 32;

    __shared__ float pl[B_][KC_];   // pooled k-slice (20 KB)
    for (int e = tid; e < B_ * (KC_ / 4); e += 256) {
        const int b   = e / (KC_ / 4);
        const int kk4 = e % (KC_ / 4);
        float4 v = ((const float4*)pooled)[(size_t)b * (D_ / 4) + (k0 / 4) + kk4];
        *(float4*)&pl[b][kk4 * 4] = v;
    }
    __syncthreads();

    float acc[8];
    #pragma unroll
    for (int r = 0; r < 8; ++r) acc[r] = 0.f;

    const float* w1p = W1 + (size_t)k0 * H1_ + j0 + jl;
    for (int kk = 0; kk < KC_; kk += 4) {
        const float w0 = w1p[(size_t)(kk + 0) * H1_];
        const float w1 = w1p[(size_t)(kk + 1) * H1_];
        const float w2 = w1p[(size_t)(kk + 2) * H1_];
        const float w3 = w1p[(size_t)(kk + 3) * H1_];
        #pragma unroll
        for (int r = 0; r < 8; ++r) {
            float4 pv = *(const float4*)&pl[b0 + r][kk];
            acc[r] = fmaf(pv.x, w0, acc[r]);
            acc[r] = fmaf(pv.y, w1, acc[r]);
            acc[r] = fmaf(pv.z, w2, acc[r]);
            acc[r] = fmaf(pv.w, w3, acc[r]);
        }
    }
    #pragma unroll
    for (int r = 0; r < 8; ++r)
        hpart[((size_t)(b0 + r) * KS_ + ks) * H1_ + j0 + jl] = acc[r];
}

// ---------------- Kernel 4: h-reduce + W2 j-slice -> emb (R15, byte-identical) -------
__global__ void mlp2(const float* __restrict__ hpart, const float* __restrict__ b1,
                     const float* __restrict__ W2, const float* __restrict__ b2,
                     float* __restrict__ out) {
    const int jt  = blockIdx.x;     // 0..4
    const int b   = blockIdx.y;     // 0..63
    const int tid = threadIdx.x;    // 0..511
    const int jl  = tid & 63;
    const int kq  = tid >> 6;       // 0..7
    const int j   = jt * 64 + jl;

    __shared__ float hrow[H1_];     // 2.56 KB
    __shared__ float pt[8][64];     // 2 KB

    const float* hb = hpart + (size_t)b * KS_ * H1_;
    for (int jj = tid; jj < H1_; jj += 512) {
        float s = b1[jj];
        #pragma unroll
        for (int ks = 0; ks < KS_; ++ks)
            s += hb[(size_t)ks * H1_ + jj];
        hrow[jj] = fmaxf(s, 0.f);
    }
    __syncthreads();

    float a0 = 0.f, a1 = 0.f, a2 = 0.f, a3 = 0.f;
    const int kbeg = kq * (H1_ / 8);
    const float* w = W2 + (size_t)kbeg * H2_ + j;
    #pragma unroll 5
    for (int k = 0; k < H1_ / 8; k += 4) {
        const float4 hv = *(const float4*)&hrow[kbeg + k];   // wave-uniform broadcast
        a0 = fmaf(hv.x, w[(size_t)(k + 0) * H2_], a0);
        a1 = fmaf(hv.y, w[(size_t)(k + 1) * H2_], a1);
        a2 = fmaf(hv.z, w[(size_t)(k + 2) * H2_], a2);
        a3 = fmaf(hv.w, w[(size_t)(k + 3) * H2_], a3);
    }
    pt[kq][jl] = (a0 + a1) + (a2 + a3);
    __syncthreads();

    if (tid < 64) {
        float e = b2[j];
        #pragma unroll
        for (int q = 0; q < 8; ++q) e += pt[q][jl];
        out[128 + (size_t)b * H2_ + j] = fmaxf(e, 0.f);
    }
}

// ---------------- Kernel 5: y = emb @ W3 + b3 (R15, byte-identical) ----------------
__global__ void mlp3(const float* __restrict__ out_emb, const float* __restrict__ W3,
                     const float* __restrict__ b3, float* __restrict__ out) {
    const int b    = blockIdx.x;
    const int lane = threadIdx.x;   // 0..63
    float s0 = 0.f, s1 = 0.f;
    #pragma unroll
    for (int i = 0; i < H2_ / 64; ++i) {
        const int jj = lane + i * 64;
        const float e = out_emb[128 + (size_t)b * H2_ + jj];
        s0 = fmaf(e, W3[(size_t)jj * 2 + 0], s0);
        s1 = fmaf(e, W3[(size_t)jj * 2 + 1], s1);
    }
    #pragma unroll
    for (int off = 32; off >= 1; off >>= 1) {
        s0 += __shfl_xor(s0, off, 64);
        s1 += __shfl_xor(s1, off, 64);
    }
    if (lane == 0) {
        out[(size_t)b * 2 + 0] = s0 + b3[0];
        out[(size_t)b * 2 + 1] = s1 + b3[1];
    }
}

extern "C" void kernel_launch(void* const* d_in, const int* in_sizes, int n_in,
                              void* d_out, int out_size, void* d_ws, size_t ws_size,
                              hipStream_t stream) {
    const float* rep  = (const float*)d_in[0];
    const int*   blen = (const int*)  d_in[1];
    const float* W1   = (const float*)d_in[2];
    const float* b1   = (const float*)d_in[3];
    const float* W2   = (const float*)d_in[4];
    const float* b2   = (const float*)d_in[5];
    const float* W3   = (const float*)d_in[6];
    const float* b3   = (const float*)d_in[7];
    float* out = (float*)d_out;

    // workspace layout (floats):
    //   part   B_*NSPLIT*D_ = 1,310,720  (5.24 MB)
    //   pooled B_*D_        =    81,920
    //   hpart  B_*KS_*H1_   =   655,360
    float* ws     = (float*)d_ws;
    float* part   = ws;
    float* pooled = part + (size_t)B_ * NSPLIT * D_;
    float* hpart  = pooled + (size_t)B_ * D_;

    pool_partial<<<dim3(NSPLIT, B_), 320, 0, stream>>>(rep, blen, part);
    pool_reduce <<<dim3(5, B_), 256, 0, stream>>>(part, blen, pooled);
    mlp1_partial<<<dim3(NJT_, KS_), 256, 0, stream>>>(pooled, W1, hpart);
    mlp2        <<<dim3(NJT2_, B_), 512, 0, stream>>>(hpart, b1, W2, b2, out);
    mlp3        <<<B_, 64, 0, stream>>>(out, W3, b3, out);
}